// Round 24
// baseline (46.167 us; speedup 1.0000x reference)
//
#include <hip/hip_runtime.h>

#define IND 256
#define KC  16   // k per chunk; 16 chunks; dbuf = 2*8*256*4 = 16 KB -> 8 blocks/CU

__global__ __launch_bounds__(256, 4)
void FeatureEncodingLayer_30374008718005_kernel(
        const float* __restrict__ X,      // [1024][256]
        const float* __restrict__ W,      // [4096][256]
        const float* __restrict__ bias,   // [4096]
        float* __restrict__ outf)         // [1024][4][4][2048] float32 = Re(kron)
{
    // Pair-interleaved, XOR-swizzled W tile (layout family verified R17/R20):
    // word (kp, u, k&1) at Ws[buf][kp][(2u+(k&1)) ^ (kp<<2)], kp = k>>1 (0..7).
    __shared__ float Ws[2][KC / 2][256];   // 16 KB

    const int tid  = threadIdx.x;
    const int lane = tid & 63;
    const int wid  = __builtin_amdgcn_readfirstlane(tid >> 6);  // wave 0..3

    const int ut = blockIdx.x & 31;    // 32 unit tiles x 128 units
    const int bt = blockIdx.x >> 5;    // 64 batch tiles x 16 batches
    const int b0 = bt * 16 + 4 * wid;  // wave's 4 batches (wave-uniform)
    const int u0 = ut * 128;
    const int p0 = ut * 64;

    const int q  = tid & 3;            // k-quad: local k = 4q..4q+3 (q 0..3)
    const int rq = tid >> 2;           // row subgroup 0..63

    const float* xc = X + (size_t)b0 * IND;   // wave-uniform -> s_load

    float acc[4][2];
#pragma unroll
    for (int i = 0; i < 4; ++i) { acc[i][0] = 0.f; acc[i][1] = 0.f; }

    float4 pf[2];
#define STAGE_LOAD(c) do {                                                     \
    _Pragma("unroll")                                                          \
    for (int j = 0; j < 2; ++j)                                                \
        pf[j] = *reinterpret_cast<const float4*>(                              \
            W + (size_t)(u0 + rq + 64 * j) * IND + (c) * KC + q * 4);          \
    } while (0)

#define STAGE_WRITE(buf) do {                                                  \
    const int kp0 = 2 * q, kp1 = 2 * q + 1;                                    \
    const int sw0 = kp0 << 2, sw1 = kp1 << 2;                                  \
    _Pragma("unroll")                                                          \
    for (int j = 0; j < 2; ++j) {                                              \
        const int u2 = 2 * (rq + 64 * j);                                      \
        *reinterpret_cast<float2*>(&Ws[buf][kp0][u2 ^ sw0]) =                  \
            make_float2(pf[j].x, pf[j].y);                                     \
        *reinterpret_cast<float2*>(&Ws[buf][kp1][u2 ^ sw1]) =                  \
            make_float2(pf[j].z, pf[j].w);                                     \
    }                                                                          \
    } while (0)

    // LDS-only barrier: global loads/stores stay in flight across it.
#define LDS_BARRIER() do {                                                     \
    asm volatile("s_waitcnt lgkmcnt(0)" ::: "memory");                         \
    __builtin_amdgcn_s_barrier();                                              \
    } while (0)

    STAGE_LOAD(0);
    STAGE_WRITE(0);
    LDS_BARRIER();

    for (int c = 0; c < IND / KC; ++c) {
        const int cur = c & 1;
        if (c < IND / KC - 1) STAGE_LOAD(c + 1);   // prefetch (no wait yet)

        // zero-slot stores: one rc per even chunk (8 total), issued after the
        // prefetch loads; never drained by the LDS-only barriers.
        if ((c & 1) == 0) {
            const int zrc = (int)((0xEDB87421u >> (2 * c)) & 0xFu);  // c/2 nibble
            float* zp = outf + (size_t)b0 * 32768 + (size_t)zrc * 2048 + p0 + lane;
#pragma unroll
            for (int i = 0; i < 4; ++i)
                zp[(size_t)i * 32768] = 0.f;
        }

        // compute: per kp, 1 conflict-free ds_read_b128 + 16 FMA
#pragma unroll
        for (int kp = 0; kp < KC / 2; ++kp) {
            const float4 wq = *reinterpret_cast<const float4*>(
                &Ws[cur][kp][(4 * lane) ^ (kp << 2)]);
            // wq = {W[2l][2kp], W[2l][2kp+1], W[2l+1][2kp], W[2l+1][2kp+1]}
            const int kg = c * KC + 2 * kp;
#pragma unroll
            for (int i = 0; i < 4; ++i) {
                const float x0 = xc[i * IND + kg];      // wave-uniform s_load
                const float x1 = xc[i * IND + kg + 1];
                acc[i][0] = fmaf(x0, wq.x, acc[i][0]);
                acc[i][0] = fmaf(x1, wq.y, acc[i][0]);
                acc[i][1] = fmaf(x0, wq.z, acc[i][1]);
                acc[i][1] = fmaf(x1, wq.w, acc[i][1]);
            }
        }
        if (c < IND / KC - 1) {
            STAGE_WRITE(cur ^ 1);                  // vmcnt wait: only its loads
            LDS_BARRIER();
        }
    }
#undef STAGE_LOAD
#undef STAGE_WRITE
#undef LDS_BARRIER

    // ---- epilogue: lane owns pair p0+lane (units u0+2lane, +1), 4 batches ----
    const float2 bv = *reinterpret_cast<const float2*>(bias + u0 + 2 * lane);

#pragma unroll
    for (int i = 0; i < 4; ++i) {
        const int b = b0 + i;
        const float tA = acc[i][0] + bv.x;
        const float tB = acc[i][1] + bv.y;
        float sA, cA, sB, cB;
        __sincosf(tA, &sA, &cA);
        __sincosf(tB, &sB, &cB);
        const float ca = 0.5f * (1.f + cA);   // cos^2(tA/2)
        const float sa = 0.5f * (1.f - cA);   // sin^2(tA/2)
        const float cb = 0.5f * (1.f + cB);
        const float sb = 0.5f * (1.f - cB);
        const float oo = 0.25f * sA * sB;     // sin(tA)/2 * sin(tB)/2

        float* bp = outf + (size_t)b * 32768 + p0 + lane;
        bp[ 0 * 2048] =  ca * cb;
        bp[ 3 * 2048] = -oo;
        bp[ 5 * 2048] =  ca * sb;
        bp[ 6 * 2048] =  oo;
        bp[ 9 * 2048] =  oo;
        bp[10 * 2048] =  sa * cb;
        bp[12 * 2048] = -oo;
        bp[15 * 2048] =  sa * sb;
    }
}

extern "C" void kernel_launch(void* const* d_in, const int* in_sizes, int n_in,
                              void* d_out, int out_size, void* d_ws, size_t ws_size,
                              hipStream_t stream) {
    const float* X  = (const float*)d_in[0];
    const float* W  = (const float*)d_in[1];
    const float* bv = (const float*)d_in[2];

    // 64 bt x 32 ut = 2048 blocks x 256 threads; 16 KB LDS + ~<=64 VGPR
    // -> 8 blocks/CU resident = 32 waves/CU: 8 independent block phases
    // per CU (vs R20's ~4-5 lockstepped) to hide SMEM/DS/store latency.
    FeatureEncodingLayer_30374008718005_kernel<<<dim3(2048), dim3(256), 0, stream>>>(
        X, W, bv, (float*)d_out);
}

// Round 25
// 42.859 us; speedup vs baseline: 1.0772x; 1.0772x over previous
//
#include <hip/hip_runtime.h>

#define IND 256
#define KC  32

__global__ __launch_bounds__(256, 4)
void FeatureEncodingLayer_30374008718005_kernel(
        const float* __restrict__ X,      // [1024][256]
        const float* __restrict__ W,      // [4096][256]
        const float* __restrict__ bias,   // [4096]
        float* __restrict__ outf)         // [1024][4][4][2048] float32 = Re(kron)
{
    // Pair-interleaved, XOR-swizzled W tile (verified R17/R20):
    // word (kp, u, k&1) at Ws[buf][kp][(2u+(k&1)) ^ ((kp&7)<<2)], kp = k>>1.
    __shared__ float Ws[2][KC / 2][256];   // 32 KB

    const int tid  = threadIdx.x;
    const int lane = tid & 63;
    const int wid  = __builtin_amdgcn_readfirstlane(tid >> 6);  // wave 0..3

    // XCD-aware swizzle (T1, bijective: 1024 = 8 XCD x 128): blocks resident
    // on one XCD get a contiguous bt range -> clustered HBM write streams.
    const int bid = ((int)blockIdx.x & 7) * 128 + ((int)blockIdx.x >> 3);

    const int ut = bid & 31;           // 32 unit tiles x 128 units
    const int bt = bid >> 5;           // 32 batch tiles x 32 batches
    const int b0 = bt * 32;
    const int u0 = ut * 128;
    const int p0 = ut * 64;

    const int q  = tid & 7;            // k-quad: local k = 4q..4q+3
    const int rq = tid >> 3;           // row subgroup 0..31

    const float* xc = X + (size_t)(b0 + 8 * wid) * IND;  // wave-uniform -> s_load

    float acc[8][2];
#pragma unroll
    for (int i = 0; i < 8; ++i) { acc[i][0] = 0.f; acc[i][1] = 0.f; }

    float4 pf[4];
#define STAGE_LOAD(c) do {                                                     \
    _Pragma("unroll")                                                          \
    for (int j = 0; j < 4; ++j)                                                \
        pf[j] = *reinterpret_cast<const float4*>(                              \
            W + (size_t)(u0 + rq + 32 * j) * IND + (c) * KC + q * 4);          \
    } while (0)

#define STAGE_WRITE(buf) do {                                                  \
    const int kp0 = 2 * q, kp1 = 2 * q + 1;                                    \
    const int sw0 = (kp0 & 7) << 2, sw1 = (kp1 & 7) << 2;                      \
    _Pragma("unroll")                                                          \
    for (int j = 0; j < 4; ++j) {                                              \
        const int u2 = 2 * (rq + 32 * j);                                      \
        *reinterpret_cast<float2*>(&Ws[buf][kp0][u2 ^ sw0]) =                  \
            make_float2(pf[j].x, pf[j].y);                                     \
        *reinterpret_cast<float2*>(&Ws[buf][kp1][u2 ^ sw1]) =                  \
            make_float2(pf[j].z, pf[j].w);                                     \
    }                                                                          \
    } while (0)

    // LDS-only barrier: global loads/stores stay in flight across it.
#define LDS_BARRIER() do {                                                     \
    asm volatile("s_waitcnt lgkmcnt(0)" ::: "memory");                         \
    __builtin_amdgcn_s_barrier();                                              \
    } while (0)

    STAGE_LOAD(0);
    STAGE_WRITE(0);
    LDS_BARRIER();

    for (int c = 0; c < IND / KC; ++c) {
        const int cur = c & 1;
        if (c < IND / KC - 1) STAGE_LOAD(c + 1);   // prefetch (no wait yet)

        // zero-slot stores: one rc per chunk, after the prefetch loads; nt =
        // no L2 allocate churn; never drained by the LDS-only barriers.
        {
            const int zrc = (int)((0xEDB87421u >> (4 * c)) & 0xFu);
            float* zp = outf + (size_t)(b0 + 8 * wid) * 32768
                       + (size_t)zrc * 2048 + p0 + lane;
#pragma unroll
            for (int i = 0; i < 8; ++i)
                __builtin_nontemporal_store(0.f, zp + (size_t)i * 32768);
        }

        // compute: per kp, 1 conflict-free ds_read_b128 + 32 FMA
#pragma unroll
        for (int kp = 0; kp < KC / 2; ++kp) {
            const int sw = (kp & 7) << 2;
            const float4 wq = *reinterpret_cast<const float4*>(
                &Ws[cur][kp][(4 * lane) ^ sw]);
            const int kg = c * KC + 2 * kp;
#pragma unroll
            for (int i = 0; i < 8; ++i) {
                const float x0 = xc[i * IND + kg];      // wave-uniform s_load
                const float x1 = xc[i * IND + kg + 1];
                acc[i][0] = fmaf(x0, wq.x, acc[i][0]);
                acc[i][0] = fmaf(x1, wq.y, acc[i][0]);
                acc[i][1] = fmaf(x0, wq.z, acc[i][1]);
                acc[i][1] = fmaf(x1, wq.w, acc[i][1]);
            }
        }
        if (c < IND / KC - 1) {
            STAGE_WRITE(cur ^ 1);                  // vmcnt wait: only its loads
            LDS_BARRIER();
        }
    }
#undef STAGE_LOAD
#undef STAGE_WRITE
#undef LDS_BARRIER

    // ---- epilogue: lane owns pair p0+lane (units u0+2lane, +1), 8 batches;
    // nonzero slots via nt stores (zeros already in flight).
    const float2 bv = *reinterpret_cast<const float2*>(bias + u0 + 2 * lane);

#pragma unroll
    for (int i = 0; i < 8; ++i) {
        const int b = b0 + 8 * wid + i;
        const float tA = acc[i][0] + bv.x;
        const float tB = acc[i][1] + bv.y;
        float sA, cA, sB, cB;
        __sincosf(tA, &sA, &cA);
        __sincosf(tB, &sB, &cB);
        const float ca = 0.5f * (1.f + cA);   // cos^2(tA/2)
        const float sa = 0.5f * (1.f - cA);   // sin^2(tA/2)
        const float cb = 0.5f * (1.f + cB);
        const float sb = 0.5f * (1.f - cB);
        const float oo = 0.25f * sA * sB;     // sin(tA)/2 * sin(tB)/2

        float* bp = outf + (size_t)b * 32768 + p0 + lane;
        __builtin_nontemporal_store( ca * cb, bp +  0 * 2048);
        __builtin_nontemporal_store(-oo,      bp +  3 * 2048);
        __builtin_nontemporal_store( ca * sb, bp +  5 * 2048);
        __builtin_nontemporal_store( oo,      bp +  6 * 2048);
        __builtin_nontemporal_store( oo,      bp +  9 * 2048);
        __builtin_nontemporal_store( sa * cb, bp + 10 * 2048);
        __builtin_nontemporal_store(-oo,      bp + 12 * 2048);
        __builtin_nontemporal_store( sa * sb, bp + 15 * 2048);
    }
}

extern "C" void kernel_launch(void* const* d_in, const int* in_sizes, int n_in,
                              void* d_out, int out_size, void* d_ws, size_t ws_size,
                              hipStream_t stream) {
    const float* X  = (const float*)d_in[0];
    const float* W  = (const float*)d_in[1];
    const float* bv = (const float*)d_in[2];

    // R20's proven shape: 1024 blocks, 256 threads, 4 blocks/CU.
    FeatureEncodingLayer_30374008718005_kernel<<<dim3(1024), dim3(256), 0, stream>>>(
        X, W, bv, (float*)d_out);
}